// Round 9
// baseline (297.982 us; speedup 1.0000x reference)
//
#include <hip/hip_runtime.h>
#include <math.h>

// Problem sizes (fixed by reference setup_inputs)
#define NP      (128 * 196)   // 25088 patches
#define PATCH   768           // elements per patch
#define ND      128           // contrastive N
#define DD      256           // contrastive D
#define TEMP_INV 10.0f        // 1 / 0.1
#define COS_EPS_F 1e-8f

#define NPW     4                 // patches per wave
#define NWAVE_R (NP / NPW)        // 6272 recon waves
#define NBLK_C  128               // contrastive blocks (1 row each)
#define NBLK    (NBLK_C + NWAVE_R) // 6400 one-wave blocks
#define CTR_OFF 65536             // byte offset of completion counter in ws

typedef float nf4 __attribute__((ext_vector_type(4)));  // native vec4 for builtins

__device__ __forceinline__ float wave_sum(float v) {
#pragma unroll
    for (int o = 32; o; o >>= 1) v += __shfl_xor(v, o);
    return v;
}
__device__ __forceinline__ float wave_max(float v) {
#pragma unroll
    for (int o = 32; o; o >>= 1) v = fmaxf(v, __shfl_xor(v, o));
    return v;
}
__device__ __forceinline__ float dot4(float4 a, float4 b) {
    return a.x * b.x + a.y * b.y + a.z * b.z + a.w * b.w;
}
__device__ __forceinline__ float ndot(nf4 a, nf4 b) {
    return a.x * b.x + a.y * b.y + a.z * b.z + a.w * b.w;
}
__device__ __forceinline__ float nsum(nf4 a) {
    return a.x + a.y + a.z + a.w;
}

// ws layout (floats):
//   [0          .. NWAVE_R)     per-wave weighted-loss partial
//   [NWAVE_R    .. 2*NWAVE_R)   per-wave mask-sum partial
//   [2*NWAVE_R  .. +128)        per-row contrastive contribution (lse_i - S_ii/T)
//   byte CTR_OFF:               u32 completion counter (memset to 0 per call)
__global__ __launch_bounds__(64) void fused_kernel(
    const float* __restrict__ preds,   // student_prob [128,256]
    const float* __restrict__ tgts,    // teacher_prob [128,256]
    const float* __restrict__ rt,      // reconstruct_target [B,L,P]
    const float* __restrict__ rp,      // reconstruct_pred   [B,L,P]
    const float* __restrict__ mask,    // [B,L]
    float* __restrict__ ws,
    unsigned* __restrict__ counter,
    float* __restrict__ out)
{
    __shared__ float4 pn4s[DD / 4];    // 1 KB, used by contrastive blocks only
    const int lane = threadIdx.x;      // block == one wave
    const int blk  = blockIdx.x;

    if (blk >= NBLK_C) {
        // ---- reconstruction: 4 patches/wave; SKIP loads where mask==0 ----
        const int gw = blk - NBLK_C;             // 0..6271
        const int p0 = gw * NPW;
        const nf4* t4 = (const nf4*)(rt + (size_t)p0 * PATCH) + lane;
        const nf4* q4 = (const nf4*)(rp + (size_t)p0 * PATCH) + lane;

        const float4 mv = *(const float4*)(mask + p0);   // wave-uniform
        const float mk[NPW] = { mv.x, mv.y, mv.z, mv.w };

        nf4 T[NPW][3], Q[NPW][3];
        // Wave-uniform guarded nontemporal loads: ~25% of patches have
        // mask==0 and contribute exactly 0 -> never read their 6 KB.
#pragma unroll
        for (int p = 0; p < NPW; ++p) {
            if (mk[p] != 0.f) {
#pragma unroll
                for (int q = 0; q < 3; ++q) {
                    T[p][q] = __builtin_nontemporal_load(&t4[p * (PATCH / 4) + q * 64]);
                    Q[p][q] = __builtin_nontemporal_load(&q4[p * (PATCH / 4) + q * 64]);
                }
            }
        }
        __builtin_amdgcn_sched_barrier(0);

        // 5 linear sums per patch (per-lane partials); zeros for skipped
        float s[NPW], ss[NPW], sp[NPW], spp[NPW], spt[NPW];
#pragma unroll
        for (int p = 0; p < NPW; ++p) {
            s[p] = ss[p] = sp[p] = spp[p] = spt[p] = 0.f;
            if (mk[p] != 0.f) {
#pragma unroll
                for (int q = 0; q < 3; ++q) {
                    nf4 t = T[p][q], pv = Q[p][q];
                    s[p]   += nsum(t);
                    ss[p]  += ndot(t, t);
                    sp[p]  += nsum(pv);
                    spp[p] += ndot(pv, pv);
                    spt[p] += ndot(pv, t);
                }
            }
        }
        // ONE butterfly phase over all 20 values (zeros pass through safely)
#pragma unroll
        for (int o = 32; o; o >>= 1) {
#pragma unroll
            for (int p = 0; p < NPW; ++p) {
                s[p]   += __shfl_xor(s[p], o);
                ss[p]  += __shfl_xor(ss[p], o);
                sp[p]  += __shfl_xor(sp[p], o);
                spp[p] += __shfl_xor(spp[p], o);
                spt[p] += __shfl_xor(spt[p], o);
            }
        }
        float acc_l = 0.f;
#pragma unroll
        for (int p = 0; p < NPW; ++p) {
            const float mean = s[p] * (1.0f / PATCH);
            const float cvar = ss[p] - s[p] * mean;              // Σ(t-mean)²
            const float var  = cvar * (1.0f / (PATCH - 1));
            const float rstd = 1.0f / sqrtf(var + 1e-6f);        // finite for zeros
            const float lsum = spp[p] - 2.f * rstd * (spt[p] - mean * sp[p])
                             + rstd * rstd * cvar;
            acc_l += lsum * (1.0f / PATCH) * mk[p];
        }
        if (lane == 0) {
            ws[gw]           = acc_l;
            ws[NWAVE_R + gw] = mk[0] + mk[1] + mk[2] + mk[3];
        }
    } else {
        // ---------------- contrastive: one row per (1-wave) block ----------
        const int i  = blk;              // row 0..127
        const float4* pg = (const float4*)preds;
        const float4* tg = (const float4*)tgts;

        // stage normalized pred row i into LDS
        float4 v = pg[(size_t)i * (DD / 4) + lane];
        float ssp = wave_sum(dot4(v, v));
        float invp = 1.0f / fmaxf(sqrtf(ssp), COS_EPS_F);
        pn4s[lane] = make_float4(v.x * invp, v.y * invp, v.z * invp, v.w * invp);
        __syncthreads();   // single wave: just a waitcnt, cheap

        // lane j reads full teacher row j: accumulate dot AND row norm inline
        const int j1 = lane, j2 = lane + 64;
        float d1 = 0.f, d2 = 0.f, n1 = 0.f, n2 = 0.f;
#pragma unroll 8
        for (int k = 0; k < DD / 4; ++k) {
            float4 c = pn4s[k];                    // LDS broadcast
            float4 a = tg[j1 * (DD / 4) + k];
            float4 b = tg[j2 * (DD / 4) + k];
            d1 += dot4(c, a);  n1 += dot4(a, a);
            d2 += dot4(c, b);  n2 += dot4(b, b);
        }
        const float s1 = d1 * (1.0f / fmaxf(sqrtf(n1), COS_EPS_F)) * TEMP_INV;
        const float s2 = d2 * (1.0f / fmaxf(sqrtf(n2), COS_EPS_F)) * TEMP_INV;
        float m = wave_max(fmaxf(s1, s2));
        float sum = wave_sum(expf(s1 - m) + expf(s2 - m));
        const float lse = m + logf(sum);
        const float pos = (i < 64) ? __shfl(s1, i) : __shfl(s2, i - 64);
        if (lane == 0) ws[2 * NWAVE_R + i] = lse - pos;
    }

    // ---------------- fenced last-block finalize ----------------
    __threadfence();                       // release partials (device scope)
    unsigned done = 0;
    if (lane == 0) done = atomicAdd(counter, 1u);
    done = __shfl(done, 0);
    if (done == NBLK - 1) {
        __threadfence();                   // acquire all partials
        const float4* w4 = (const float4*)ws;
        float a = 0.f, b = 0.f;
        for (int i = lane; i < NWAVE_R / 4; i += 64) {          // loss partials
            float4 v = w4[i];
            a += v.x + v.y + v.z + v.w;
        }
        for (int i = lane; i < NWAVE_R / 4; i += 64) {          // mask partials
            float4 v = w4[NWAVE_R / 4 + i];
            b += v.x + v.y + v.z + v.w;
        }
        float c = ws[2 * NWAVE_R + lane] + ws[2 * NWAVE_R + 64 + lane];
        a = wave_sum(a); b = wave_sum(b); c = wave_sum(c);
        if (lane == 0) {
            const float recon = a / b;
            const float contr = c * (1.0f / ND);
            out[0] = recon;
            out[1] = contr;
            out[2] = recon + contr;
        }
    }
}

extern "C" void kernel_launch(void* const* d_in, const int* in_sizes, int n_in,
                              void* d_out, int out_size, void* d_ws, size_t ws_size,
                              hipStream_t stream) {
    const float* student = (const float*)d_in[0];
    const float* teacher = (const float*)d_in[1];
    const float* rt      = (const float*)d_in[2];
    const float* rp      = (const float*)d_in[3];
    const float* mask    = (const float*)d_in[4];
    float* ws  = (float*)d_ws;
    unsigned* counter = (unsigned*)((char*)d_ws + CTR_OFF);
    float* out = (float*)d_out;

    hipMemsetAsync(counter, 0, sizeof(unsigned), stream);
    hipLaunchKernelGGL(fused_kernel, dim3(NBLK), dim3(64), 0, stream,
                       student, teacher, rt, rp, mask, ws, counter, out);
}

// Round 10
// 39.890 us; speedup vs baseline: 7.4701x; 7.4701x over previous
//
#include <hip/hip_runtime.h>
#include <math.h>

// Problem sizes (fixed by reference setup_inputs)
#define NP      (128 * 196)   // 25088 patches
#define PATCH   768           // elements per patch
#define ND      128           // contrastive N
#define DD      256           // contrastive D
#define TEMP_INV 10.0f        // 1 / 0.1
#define COS_EPS_F 1e-8f

#define NPW     4                 // patches per wave
#define NWAVE_R (NP / NPW)        // 6272 recon waves
#define NB_R    (NWAVE_R / 4)     // 1568 recon blocks (4 waves each)
#define NB_C    32                // contrastive blocks (4 rows each -> 128 rows)

typedef float nf4 __attribute__((ext_vector_type(4)));  // native vec4

__device__ __forceinline__ float wave_sum(float v) {
#pragma unroll
    for (int o = 32; o; o >>= 1) v += __shfl_xor(v, o);
    return v;
}
__device__ __forceinline__ float wave_max(float v) {
#pragma unroll
    for (int o = 32; o; o >>= 1) v = fmaxf(v, __shfl_xor(v, o));
    return v;
}
__device__ __forceinline__ float dot4(float4 a, float4 b) {
    return a.x * b.x + a.y * b.y + a.z * b.z + a.w * b.w;
}
__device__ __forceinline__ float ndot(nf4 a, nf4 b) {
    return a.x * b.x + a.y * b.y + a.z * b.z + a.w * b.w;
}
__device__ __forceinline__ float nsum(nf4 a) {
    return a.x + a.y + a.z + a.w;
}

// ws layout (floats):
//   [0          .. NWAVE_R)     per-wave weighted-loss partial
//   [NWAVE_R    .. 2*NWAVE_R)   per-wave mask-sum partial
//   [2*NWAVE_R  .. +128)        per-row contrastive contribution (lse_i - S_ii/T)
__global__ __launch_bounds__(256, 2) void partials_kernel(
    const float* __restrict__ preds,   // student_prob [128,256]
    const float* __restrict__ tgts,    // teacher_prob [128,256]
    const float* __restrict__ rt,      // reconstruct_target [B,L,P]
    const float* __restrict__ rp,      // reconstruct_pred   [B,L,P]
    const float* __restrict__ mask,    // [B,L]
    float* __restrict__ ws)
{
    const int tid  = threadIdx.x;
    const int w    = tid >> 6;
    const int lane = tid & 63;
    const int blk  = blockIdx.x;

    if (blk >= NB_C) {
        // ---- reconstruction: 4 patches/wave; mask-skip; L2/L3-bypass reads ----
        const int gw = (blk - NB_C) * 4 + w;     // 0..6271
        const int p0 = gw * NPW;

        // mask first: it's the serial head dependency for all guarded loads
        const float4 mv = *(const float4*)(mask + p0);   // wave-uniform
        const float mk[NPW] = { mv.x, mv.y, mv.z, mv.w };

        const nf4* t4 = (const nf4*)(rt + (size_t)p0 * PATCH) + lane;
        const nf4* q4 = (const nf4*)(rp + (size_t)p0 * PATCH) + lane;

        nf4 T[NPW][3], Q[NPW][3];
        // Guarded per-patch asm blobs: 6 nt+sc1 loads each, NO waitcnt inside.
        // All issued blobs stay in flight until the single waitcnt below.
        // nt = non-temporal, sc1 = system scope (bypass L2/L3 allocate path).
#pragma unroll
        for (int p = 0; p < NPW; ++p) {
            if (mk[p] != 0.f) {
                const nf4* ta = t4 + p * (PATCH / 4);
                const nf4* qa = q4 + p * (PATCH / 4);
                asm volatile(
                    "global_load_dwordx4 %0, %[a], off nt sc1\n\t"
                    "global_load_dwordx4 %1, %[a], off offset:1024 nt sc1\n\t"
                    "global_load_dwordx4 %2, %[a], off offset:2048 nt sc1\n\t"
                    "global_load_dwordx4 %3, %[b], off nt sc1\n\t"
                    "global_load_dwordx4 %4, %[b], off offset:1024 nt sc1\n\t"
                    "global_load_dwordx4 %5, %[b], off offset:2048 nt sc1"
                    : "=&v"(T[p][0]), "=&v"(T[p][1]), "=&v"(T[p][2]),
                      "=&v"(Q[p][0]), "=&v"(Q[p][1]), "=&v"(Q[p][2])
                    : [a]"v"(ta), [b]"v"(qa));
            }
        }
        // Drain all outstanding loads, then fence the scheduler so no
        // consumer is hoisted above the waitcnt (rule #18).
        asm volatile("s_waitcnt vmcnt(0)" ::: "memory");
        __builtin_amdgcn_sched_barrier(0);

        // 5 linear sums per patch (per-lane partials); zeros for skipped
        float s[NPW], ss[NPW], sp[NPW], spp[NPW], spt[NPW];
#pragma unroll
        for (int p = 0; p < NPW; ++p) {
            s[p] = ss[p] = sp[p] = spp[p] = spt[p] = 0.f;
            if (mk[p] != 0.f) {
#pragma unroll
                for (int q = 0; q < 3; ++q) {
                    nf4 t = T[p][q], pv = Q[p][q];
                    s[p]   += nsum(t);
                    ss[p]  += ndot(t, t);
                    sp[p]  += nsum(pv);
                    spp[p] += ndot(pv, pv);
                    spt[p] += ndot(pv, t);
                }
            }
        }
        // ONE butterfly phase over all 20 values (zeros pass through safely)
#pragma unroll
        for (int o = 32; o; o >>= 1) {
#pragma unroll
            for (int p = 0; p < NPW; ++p) {
                s[p]   += __shfl_xor(s[p], o);
                ss[p]  += __shfl_xor(ss[p], o);
                sp[p]  += __shfl_xor(sp[p], o);
                spp[p] += __shfl_xor(spp[p], o);
                spt[p] += __shfl_xor(spt[p], o);
            }
        }
        float acc_l = 0.f;
#pragma unroll
        for (int p = 0; p < NPW; ++p) {
            const float mean = s[p] * (1.0f / PATCH);
            const float cvar = ss[p] - s[p] * mean;              // Σ(t-mean)²
            const float var  = cvar * (1.0f / (PATCH - 1));
            const float rstd = 1.0f / sqrtf(var + 1e-6f);        // finite for zeros
            const float lsum = spp[p] - 2.f * rstd * (spt[p] - mean * sp[p])
                             + rstd * rstd * cvar;
            acc_l += lsum * (1.0f / PATCH) * mk[p];
        }
        if (lane == 0) {
            ws[gw]           = acc_l;
            ws[NWAVE_R + gw] = mk[0] + mk[1] + mk[2] + mk[3];
        }
    } else {
        // ---------------- contrastive per-row contributions ----------------
        __shared__ float4 pn4s[4][DD / 4];
        const int i  = blk * 4 + w;      // row 0..127
        const float4* pg = (const float4*)preds;
        const float4* tg = (const float4*)tgts;

        // stage normalized pred row i into LDS (wave-local)
        float4 v = pg[(size_t)i * (DD / 4) + lane];
        float ssp = wave_sum(dot4(v, v));
        float invp = 1.0f / fmaxf(sqrtf(ssp), COS_EPS_F);
        pn4s[w][lane] = make_float4(v.x * invp, v.y * invp, v.z * invp, v.w * invp);
        __syncthreads();

        // lane j reads full teacher row j: accumulate dot AND row norm inline
        const int j1 = lane, j2 = lane + 64;
        float d1 = 0.f, d2 = 0.f, n1 = 0.f, n2 = 0.f;
#pragma unroll 8
        for (int k = 0; k < DD / 4; ++k) {
            float4 c = pn4s[w][k];                 // LDS broadcast
            float4 a = tg[j1 * (DD / 4) + k];
            float4 b = tg[j2 * (DD / 4) + k];
            d1 += dot4(c, a);  n1 += dot4(a, a);
            d2 += dot4(c, b);  n2 += dot4(b, b);
        }
        const float s1 = d1 * (1.0f / fmaxf(sqrtf(n1), COS_EPS_F)) * TEMP_INV;
        const float s2 = d2 * (1.0f / fmaxf(sqrtf(n2), COS_EPS_F)) * TEMP_INV;
        float m = wave_max(fmaxf(s1, s2));
        float sum = wave_sum(expf(s1 - m) + expf(s2 - m));
        const float lse = m + logf(sum);
        const float pos = (i < 64) ? __shfl(s1, i) : __shfl(s2, i - 64);
        if (lane == 0) ws[2 * NWAVE_R + i] = lse - pos;
    }
}

__global__ __launch_bounds__(256) void finalize_kernel(
    const float* __restrict__ ws, float* __restrict__ out)
{
    __shared__ float s_red[12];
    const int tid = threadIdx.x, w = tid >> 6, lane = tid & 63;
    float a = 0.f, b = 0.f, c = 0.f;
    for (int i = tid; i < NWAVE_R; i += 256) {
        a += ws[i];
        b += ws[NWAVE_R + i];
    }
    if (tid < ND) c = ws[2 * NWAVE_R + tid];
    a = wave_sum(a); b = wave_sum(b); c = wave_sum(c);
    if (lane == 0) { s_red[w] = a; s_red[4 + w] = b; s_red[8 + w] = c; }
    __syncthreads();
    if (tid == 0) {
        float la = 0.f, lb = 0.f, lc = 0.f;
#pragma unroll
        for (int k = 0; k < 4; ++k) {
            la += s_red[k]; lb += s_red[4 + k]; lc += s_red[8 + k];
        }
        const float recon = la / lb;
        const float contr = lc / (float)ND;
        out[0] = recon;
        out[1] = contr;
        out[2] = recon + contr;
    }
}

extern "C" void kernel_launch(void* const* d_in, const int* in_sizes, int n_in,
                              void* d_out, int out_size, void* d_ws, size_t ws_size,
                              hipStream_t stream) {
    const float* student = (const float*)d_in[0];
    const float* teacher = (const float*)d_in[1];
    const float* rt      = (const float*)d_in[2];
    const float* rp      = (const float*)d_in[3];
    const float* mask    = (const float*)d_in[4];
    float* ws  = (float*)d_ws;
    float* out = (float*)d_out;

    hipLaunchKernelGGL(partials_kernel, dim3(NB_C + NB_R), dim3(256), 0, stream,
                       student, teacher, rt, rp, mask, ws);
    hipLaunchKernelGGL(finalize_kernel, dim3(1), dim3(256), 0, stream, ws, out);
}

// Round 11
// 32.953 us; speedup vs baseline: 9.0427x; 1.2105x over previous
//
#include <hip/hip_runtime.h>
#include <math.h>

// Problem sizes (fixed by reference setup_inputs)
#define NP      (128 * 196)   // 25088 patches
#define PATCH   768           // elements per patch
#define ND      128           // contrastive N
#define DD      256           // contrastive D
#define TEMP_INV 10.0f        // 1 / 0.1
#define COS_EPS_F 1e-8f

#define NPW     4                 // patches per wave
#define NWAVE_R (NP / NPW)        // 6272 recon waves
#define NB_R    (NWAVE_R / 4)     // 1568 recon blocks (4 waves each)
#define NB_C    32                // contrastive blocks (4 rows each -> 128 rows)

typedef float nf4 __attribute__((ext_vector_type(4)));  // native vec4

__device__ __forceinline__ float wave_sum(float v) {
#pragma unroll
    for (int o = 32; o; o >>= 1) v += __shfl_xor(v, o);
    return v;
}
__device__ __forceinline__ float wave_max(float v) {
#pragma unroll
    for (int o = 32; o; o >>= 1) v = fmaxf(v, __shfl_xor(v, o));
    return v;
}
__device__ __forceinline__ float dot4(float4 a, float4 b) {
    return a.x * b.x + a.y * b.y + a.z * b.z + a.w * b.w;
}
__device__ __forceinline__ float ndot(nf4 a, nf4 b) {
    return a.x * b.x + a.y * b.y + a.z * b.z + a.w * b.w;
}
__device__ __forceinline__ float nsum(nf4 a) {
    return a.x + a.y + a.z + a.w;
}

// ws layout (floats):
//   [0        .. NB_R)       per-BLOCK weighted-loss partial (1568)
//   [NB_R     .. 2*NB_R)     per-BLOCK mask-sum partial      (1568)
//   [2*NB_R   .. +128)       per-row contrastive contribution (lse_i - S_ii/T)
__global__ __launch_bounds__(256, 2) void partials_kernel(
    const float* __restrict__ preds,   // student_prob [128,256]
    const float* __restrict__ tgts,    // teacher_prob [128,256]
    const float* __restrict__ rt,      // reconstruct_target [B,L,P]
    const float* __restrict__ rp,      // reconstruct_pred   [B,L,P]
    const float* __restrict__ mask,    // [B,L]
    float* __restrict__ ws)
{
    const int tid  = threadIdx.x;
    const int w    = tid >> 6;
    const int lane = tid & 63;
    const int blk  = blockIdx.x;

    if (blk >= NB_C) {
        // ---- reconstruction: 4 patches/wave; mask-skip; nt+sc1 reads ----
        __shared__ float red[8];
        const int br = blk - NB_C;               // recon block id 0..1567
        const int gw = br * 4 + w;               // 0..6271
        const int p0 = gw * NPW;

        // mask first: it's the serial head dependency for all guarded loads
        const float4 mv = *(const float4*)(mask + p0);   // wave-uniform
        const float mk[NPW] = { mv.x, mv.y, mv.z, mv.w };

        const nf4* t4 = (const nf4*)(rt + (size_t)p0 * PATCH) + lane;
        const nf4* q4 = (const nf4*)(rp + (size_t)p0 * PATCH) + lane;

        nf4 T[NPW][3], Q[NPW][3];
        // Guarded per-patch asm blobs: 6 nt+sc1 loads each, NO waitcnt inside.
#pragma unroll
        for (int p = 0; p < NPW; ++p) {
            if (mk[p] != 0.f) {
                const nf4* ta = t4 + p * (PATCH / 4);
                const nf4* qa = q4 + p * (PATCH / 4);
                asm volatile(
                    "global_load_dwordx4 %0, %[a], off nt sc1\n\t"
                    "global_load_dwordx4 %1, %[a], off offset:1024 nt sc1\n\t"
                    "global_load_dwordx4 %2, %[a], off offset:2048 nt sc1\n\t"
                    "global_load_dwordx4 %3, %[b], off nt sc1\n\t"
                    "global_load_dwordx4 %4, %[b], off offset:1024 nt sc1\n\t"
                    "global_load_dwordx4 %5, %[b], off offset:2048 nt sc1"
                    : "=&v"(T[p][0]), "=&v"(T[p][1]), "=&v"(T[p][2]),
                      "=&v"(Q[p][0]), "=&v"(Q[p][1]), "=&v"(Q[p][2])
                    : [a]"v"(ta), [b]"v"(qa));
            }
        }
        // Drain all outstanding loads, then fence the scheduler (rule #18).
        asm volatile("s_waitcnt vmcnt(0)" ::: "memory");
        __builtin_amdgcn_sched_barrier(0);

        // 5 linear sums per patch (per-lane partials); zeros for skipped
        float s[NPW], ss[NPW], sp[NPW], spp[NPW], spt[NPW];
#pragma unroll
        for (int p = 0; p < NPW; ++p) {
            s[p] = ss[p] = sp[p] = spp[p] = spt[p] = 0.f;
            if (mk[p] != 0.f) {
#pragma unroll
                for (int q = 0; q < 3; ++q) {
                    nf4 t = T[p][q], pv = Q[p][q];
                    s[p]   += nsum(t);
                    ss[p]  += ndot(t, t);
                    sp[p]  += nsum(pv);
                    spp[p] += ndot(pv, pv);
                    spt[p] += ndot(pv, t);
                }
            }
        }
        // ONE butterfly phase over all 20 values (zeros pass through safely)
#pragma unroll
        for (int o = 32; o; o >>= 1) {
#pragma unroll
            for (int p = 0; p < NPW; ++p) {
                s[p]   += __shfl_xor(s[p], o);
                ss[p]  += __shfl_xor(ss[p], o);
                sp[p]  += __shfl_xor(sp[p], o);
                spp[p] += __shfl_xor(spp[p], o);
                spt[p] += __shfl_xor(spt[p], o);
            }
        }
        float acc_l = 0.f;
#pragma unroll
        for (int p = 0; p < NPW; ++p) {
            const float mean = s[p] * (1.0f / PATCH);
            const float cvar = ss[p] - s[p] * mean;              // Σ(t-mean)²
            const float var  = cvar * (1.0f / (PATCH - 1));
            const float rstd = 1.0f / sqrtf(var + 1e-6f);        // finite for zeros
            const float lsum = spp[p] - 2.f * rstd * (spt[p] - mean * sp[p])
                             + rstd * rstd * cvar;
            acc_l += lsum * (1.0f / PATCH) * mk[p];
        }
        // block-level reduction: 4 waves -> 1 partial pair per block
        if (lane == 0) {
            red[w]     = acc_l;
            red[4 + w] = mk[0] + mk[1] + mk[2] + mk[3];
        }
        __syncthreads();
        if (tid == 0) {
            ws[br]        = red[0] + red[1] + red[2] + red[3];
            ws[NB_R + br] = red[4] + red[5] + red[6] + red[7];
        }
    } else {
        // ---------------- contrastive per-row contributions ----------------
        __shared__ float4 pn4s[4][DD / 4];
        const int i  = blk * 4 + w;      // row 0..127
        const float4* pg = (const float4*)preds;
        const float4* tg = (const float4*)tgts;

        // stage normalized pred row i into LDS (wave-local)
        float4 v = pg[(size_t)i * (DD / 4) + lane];
        float ssp = wave_sum(dot4(v, v));
        float invp = 1.0f / fmaxf(sqrtf(ssp), COS_EPS_F);
        pn4s[w][lane] = make_float4(v.x * invp, v.y * invp, v.z * invp, v.w * invp);
        __syncthreads();

        // lane j reads full teacher row j: accumulate dot AND row norm inline
        const int j1 = lane, j2 = lane + 64;
        float d1 = 0.f, d2 = 0.f, n1 = 0.f, n2 = 0.f;
#pragma unroll 8
        for (int k = 0; k < DD / 4; ++k) {
            float4 c = pn4s[w][k];                 // LDS broadcast
            float4 a = tg[j1 * (DD / 4) + k];
            float4 b = tg[j2 * (DD / 4) + k];
            d1 += dot4(c, a);  n1 += dot4(a, a);
            d2 += dot4(c, b);  n2 += dot4(b, b);
        }
        const float s1 = d1 * (1.0f / fmaxf(sqrtf(n1), COS_EPS_F)) * TEMP_INV;
        const float s2 = d2 * (1.0f / fmaxf(sqrtf(n2), COS_EPS_F)) * TEMP_INV;
        float m = wave_max(fmaxf(s1, s2));
        float sum = wave_sum(expf(s1 - m) + expf(s2 - m));
        const float lse = m + logf(sum);
        const float pos = (i < 64) ? __shfl(s1, i) : __shfl(s2, i - 64);
        if (lane == 0) ws[2 * NB_R + i] = lse - pos;
    }
}

__global__ __launch_bounds__(256) void finalize_kernel(
    const float* __restrict__ ws, float* __restrict__ out)
{
    __shared__ float s_red[12];
    const int tid = threadIdx.x, w = tid >> 6, lane = tid & 63;
    const float4* w4 = (const float4*)ws;
    float a = 0.f, b = 0.f, c = 0.f;
    // NB_R/4 = 392 float4 per array; threads read <=2 each (one round-trip)
#pragma unroll 2
    for (int i = tid; i < NB_R / 4; i += 256) {
        float4 u = w4[i];                 // loss partials
        float4 v = w4[NB_R / 4 + i];      // mask partials
        a += u.x + u.y + u.z + u.w;
        b += v.x + v.y + v.z + v.w;
    }
    if (tid < ND) c = ws[2 * NB_R + tid];
    a = wave_sum(a); b = wave_sum(b); c = wave_sum(c);
    if (lane == 0) { s_red[w] = a; s_red[4 + w] = b; s_red[8 + w] = c; }
    __syncthreads();
    if (tid == 0) {
        float la = 0.f, lb = 0.f, lc = 0.f;
#pragma unroll
        for (int k = 0; k < 4; ++k) {
            la += s_red[k]; lb += s_red[4 + k]; lc += s_red[8 + k];
        }
        const float recon = la / lb;
        const float contr = lc / (float)ND;
        out[0] = recon;
        out[1] = contr;
        out[2] = recon + contr;
    }
}

extern "C" void kernel_launch(void* const* d_in, const int* in_sizes, int n_in,
                              void* d_out, int out_size, void* d_ws, size_t ws_size,
                              hipStream_t stream) {
    const float* student = (const float*)d_in[0];
    const float* teacher = (const float*)d_in[1];
    const float* rt      = (const float*)d_in[2];
    const float* rp      = (const float*)d_in[3];
    const float* mask    = (const float*)d_in[4];
    float* ws  = (float*)d_ws;
    float* out = (float*)d_out;

    hipLaunchKernelGGL(partials_kernel, dim3(NB_C + NB_R), dim3(256), 0, stream,
                       student, teacher, rt, rp, mask, ws);
    hipLaunchKernelGGL(finalize_kernel, dim3(1), dim3(256), 0, stream, ws, out);
}